// Round 1
// baseline (9052.305 us; speedup 1.0000x reference)
//
#include <hip/hip_runtime.h>
#include <hip/hip_bf16.h>

typedef __hip_bfloat16 bf16;

// ---------------------------------------------------------------------------
// helpers
// ---------------------------------------------------------------------------
__device__ inline float load1(const float* p) { return *p; }
__device__ inline float load1(const bf16* p) { return __bfloat162float(*p); }

__device__ inline void block_reduce_atomic(float v, float* dst) {
    // wave (64) shuffle reduce, then cross-wave via LDS, one atomic per block
    #pragma unroll
    for (int o = 32; o > 0; o >>= 1) v += __shfl_down(v, o, 64);
    __shared__ float ws[8];
    const int lane = threadIdx.x & 63;
    const int wid  = threadIdx.x >> 6;
    if (lane == 0) ws[wid] = v;
    __syncthreads();
    if (threadIdx.x == 0) {
        float s = 0.f;
        const int nw = (blockDim.x + 63) >> 6;
        for (int i = 0; i < nw; ++i) s += ws[i];
        atomicAdd(dst, s);
    }
}

// ---------------------------------------------------------------------------
// small kernels
// ---------------------------------------------------------------------------
__global__ void zero_accs_kernel(float* accs) {
    if (threadIdx.x < 8) accs[threadIdx.x] = 0.f;
}

__global__ void mse_kernel(const float* __restrict__ a, const float* __restrict__ b,
                           float* __restrict__ acc, int n) {
    float s = 0.f;
    for (int i = blockIdx.x * blockDim.x + threadIdx.x; i < n; i += gridDim.x * blockDim.x) {
        float d = a[i] - b[i];
        s += d * d;
    }
    block_reduce_atomic(s, acc);
}

// SSIM over (B,256,256) valid 250x250, win=7, skimage formulas
__global__ void ssim_kernel(const float* __restrict__ x, const float* __restrict__ y,
                            float* __restrict__ acc) {
    const int b = blockIdx.y;
    const int t = blockIdx.x * blockDim.x + threadIdx.x;
    float S = 0.f;
    if (t < 250 * 250) {
        const int i = t / 250, j = t - (t / 250) * 250;
        const float* xp = x + (size_t)b * 65536;
        const float* yp = y + (size_t)b * 65536;
        float sx = 0.f, sy = 0.f, sxx = 0.f, syy = 0.f, sxy = 0.f;
        #pragma unroll
        for (int dy = 0; dy < 7; ++dy) {
            const float* xr = xp + (size_t)(i + dy) * 256 + j;
            const float* yr = yp + (size_t)(i + dy) * 256 + j;
            #pragma unroll
            for (int dx = 0; dx < 7; ++dx) {
                float a = xr[dx], c = yr[dx];
                sx += a; sy += c;
                sxx += a * a; syy += c * c; sxy += a * c;
            }
        }
        const float inv = 1.f / 49.f;
        const float cn  = 49.f / 48.f;
        float ux = sx * inv, uy = sy * inv;
        float vx  = cn * (sxx * inv - ux * ux);
        float vy  = cn * (syy * inv - uy * uy);
        float vxy = cn * (sxy * inv - ux * uy);
        const float C1 = 1e-4f, C2 = 9e-4f;
        S = ((2.f * ux * uy + C1) * (2.f * vxy + C2)) /
            ((ux * ux + uy * uy + C1) * (vx + vy + C2));
    }
    block_reduce_atomic(S, acc);
}

__global__ void sqdiff_kernel(const bf16* __restrict__ a, const bf16* __restrict__ b,
                              float* __restrict__ acc, int n) {
    float s = 0.f;
    for (int i = blockIdx.x * blockDim.x + threadIdx.x; i < n; i += gridDim.x * blockDim.x) {
        float d = __bfloat162float(a[i]) - __bfloat162float(b[i]);
        s += d * d;
    }
    block_reduce_atomic(s, acc);
}

__global__ void finalize_kernel(const float* __restrict__ accs, float* __restrict__ out) {
    if (threadIdx.x == 0) {
        float mse    = accs[0] * (1.f / 524288.f);
        float ssim_l = 1.f - accs[1] * (1.f / 500000.f);
        float perc   = accs[2] * (1.f / 33554432.f);
        out[0] = mse + 0.5f * ssim_l + 0.1f * perc;
        out[1] = mse;
        out[2] = ssim_l;
        out[3] = perc;
    }
}

// ---------------------------------------------------------------------------
// direct 3x3 conv, SAME, NCHW, relu epilogue, optional fused 2x2 maxpool.
// block = (16,16); each thread: 2x2 pixels x 4 output channels.
// block tile: 32x32 pixels, 4 output channels, one batch image.
// ---------------------------------------------------------------------------
template <typename TIN, bool POOL>
__global__ __launch_bounds__(256) void conv3x3_kernel(
    const TIN* __restrict__ in,    // (B, CIN, H, W)
    const float* __restrict__ w,   // (COUT, CIN, 3, 3)
    const float* __restrict__ bias,// (COUT)
    bf16* __restrict__ out,        // (B, COUT, H, W) or pooled (B,COUT,H/2,W/2)
    int CIN, int COUT, int H, int W) {
    const int tx = threadIdx.x;           // 0..15
    const int ty = threadIdx.y;           // 0..15
    const int tileX = blockIdx.x * 32;
    const int tileY = blockIdx.y * 32;
    const int ngrp = COUT >> 2;
    const int b    = blockIdx.z / ngrp;
    const int co0  = (blockIdx.z - b * ngrp) << 2;

    __shared__ float sm[34 * 34];

    float acc[4][2][2];
    #pragma unroll
    for (int c = 0; c < 4; ++c) {
        float bv = bias[co0 + c];
        acc[c][0][0] = bv; acc[c][0][1] = bv;
        acc[c][1][0] = bv; acc[c][1][1] = bv;
    }

    const int y0 = tileY + 2 * ty;
    const int x0 = tileX + 2 * tx;
    const size_t HW = (size_t)H * W;
    const int tid = ty * 16 + tx;

    for (int ci = 0; ci < CIN; ++ci) {
        // stage 34x34 halo tile of channel ci into LDS
        const TIN* inp = in + ((size_t)b * CIN + ci) * HW;
        #pragma unroll
        for (int k = 0; k < 5; ++k) {
            int idx = tid + k * 256;
            if (idx < 34 * 34) {
                int ly = idx / 34, lx = idx - ly * 34;
                int gy = tileY + ly - 1, gx = tileX + lx - 1;
                float v = 0.f;
                if ((unsigned)gy < (unsigned)H && (unsigned)gx < (unsigned)W)
                    v = load1(inp + (size_t)gy * W + gx);
                sm[idx] = v;
            }
        }
        __syncthreads();

        // 4x4 input patch into registers
        float p[4][4];
        #pragma unroll
        for (int i = 0; i < 4; ++i)
            #pragma unroll
            for (int j = 0; j < 4; ++j)
                p[i][j] = sm[(2 * ty + i) * 34 + (2 * tx + j)];

        const float* wp = w + ((size_t)co0 * CIN + ci) * 9;  // wave-uniform -> s_load
        #pragma unroll
        for (int c = 0; c < 4; ++c) {
            #pragma unroll
            for (int dy = 0; dy < 3; ++dy)
                #pragma unroll
                for (int dx = 0; dx < 3; ++dx) {
                    float wk = wp[(size_t)c * CIN * 9 + dy * 3 + dx];
                    acc[c][0][0] += p[dy][dx] * wk;
                    acc[c][0][1] += p[dy][dx + 1] * wk;
                    acc[c][1][0] += p[dy + 1][dx] * wk;
                    acc[c][1][1] += p[dy + 1][dx + 1] * wk;
                }
        }
        __syncthreads();
    }

    if (POOL) {
        // relu(max 2x2) == max(2x2) then relu
        const int Ho = H >> 1, Wo = W >> 1;
        #pragma unroll
        for (int c = 0; c < 4; ++c) {
            float m = fmaxf(fmaxf(acc[c][0][0], acc[c][0][1]),
                            fmaxf(acc[c][1][0], acc[c][1][1]));
            m = fmaxf(m, 0.f);
            out[(((size_t)b * COUT + co0 + c) * Ho + (y0 >> 1)) * Wo + (x0 >> 1)] =
                __float2bfloat16(m);
        }
    } else {
        #pragma unroll
        for (int c = 0; c < 4; ++c)
            #pragma unroll
            for (int i = 0; i < 2; ++i)
                #pragma unroll
                for (int j = 0; j < 2; ++j) {
                    float v = fmaxf(acc[c][i][j], 0.f);
                    out[(((size_t)b * COUT + co0 + c) * H + (y0 + i)) * W + (x0 + j)] =
                        __float2bfloat16(v);
                }
    }
}

// ---------------------------------------------------------------------------
// launch
// ---------------------------------------------------------------------------
extern "C" void kernel_launch(void* const* d_in, const int* in_sizes, int n_in,
                              void* d_out, int out_size, void* d_ws, size_t ws_size,
                              hipStream_t stream) {
    const float* sr = (const float*)d_in[0];
    const float* hr = (const float*)d_in[1];
    const float* w1 = (const float*)d_in[2];
    const float* b1 = (const float*)d_in[3];
    const float* w2 = (const float*)d_in[4];
    const float* b2 = (const float*)d_in[5];
    const float* w3 = (const float*)d_in[6];
    const float* b3 = (const float*)d_in[7];
    const float* w4 = (const float*)d_in[8];
    const float* b4 = (const float*)d_in[9];
    float* out = (float*)d_out;

    // workspace layout (per batch image: h1 8MiB, max(pooled,h4) 8MiB, F 8MiB)
    const size_t PER_BATCH = 8u * 1024u * 1024u;  // bytes per buffer per batch
    char* ws = (char*)d_ws;
    float* accs = (float*)ws;
    const size_t base = 256;

    // choose batch chunk size nb (divisor of 8) that fits in ws_size
    int nb = 8;
    while (nb > 1 && base + 3u * PER_BATCH * (size_t)nb > ws_size) nb >>= 1;

    bf16* A  = (bf16*)(ws + base);
    bf16* Bb = (bf16*)(ws + base + PER_BATCH * (size_t)nb);
    bf16* F  = (bf16*)(ws + base + 2u * PER_BATCH * (size_t)nb);

    zero_accs_kernel<<<1, 32, 0, stream>>>(accs);
    mse_kernel<<<2048, 256, 0, stream>>>(sr, hr, accs + 0, 524288);
    ssim_kernel<<<dim3(245, 8), 256, 0, stream>>>(sr, hr, accs + 1);

    const dim3 blk(16, 16);
    for (int b0 = 0; b0 < 8; b0 += nb) {
        const float* srb = sr + (size_t)b0 * 65536;
        const float* hrb = hr + (size_t)b0 * 65536;
        // sr features -> F
        conv3x3_kernel<float, false><<<dim3(8, 8, nb * 16), blk, 0, stream>>>(
            srb, w1, b1, A, 1, 64, 256, 256);
        conv3x3_kernel<bf16, true><<<dim3(8, 8, nb * 32), blk, 0, stream>>>(
            A, w2, b2, Bb, 64, 128, 256, 256);
        conv3x3_kernel<bf16, false><<<dim3(4, 4, nb * 64), blk, 0, stream>>>(
            Bb, w3, b3, A, 128, 256, 128, 128);
        conv3x3_kernel<bf16, false><<<dim3(4, 4, nb * 64), blk, 0, stream>>>(
            A, w4, b4, F, 256, 256, 128, 128);
        // hr features -> Bb
        conv3x3_kernel<float, false><<<dim3(8, 8, nb * 16), blk, 0, stream>>>(
            hrb, w1, b1, A, 1, 64, 256, 256);
        conv3x3_kernel<bf16, true><<<dim3(8, 8, nb * 32), blk, 0, stream>>>(
            A, w2, b2, Bb, 64, 128, 256, 256);
        conv3x3_kernel<bf16, false><<<dim3(4, 4, nb * 64), blk, 0, stream>>>(
            Bb, w3, b3, A, 128, 256, 128, 128);
        conv3x3_kernel<bf16, false><<<dim3(4, 4, nb * 64), blk, 0, stream>>>(
            A, w4, b4, Bb, 256, 256, 128, 128);
        // accumulate sum((sr_f - hr_f)^2) for this chunk
        sqdiff_kernel<<<4096, 256, 0, stream>>>(F, Bb, accs + 2, nb * 4194304);
    }

    finalize_kernel<<<1, 1, 0, stream>>>(accs, out);
}

// Round 2
// 1619.799 us; speedup vs baseline: 5.5885x; 5.5885x over previous
//
#include <hip/hip_runtime.h>
#include <hip/hip_bf16.h>

typedef __hip_bfloat16 bf16;
typedef __attribute__((ext_vector_type(8))) __bf16 bf16x8;
typedef __attribute__((ext_vector_type(4))) float f32x4;
typedef __attribute__((ext_vector_type(4))) unsigned short us4;
typedef __attribute__((ext_vector_type(8))) unsigned short us8;

__device__ inline unsigned short f2bf(float f) {
    __hip_bfloat16 h = __float2bfloat16(f);
    return __builtin_bit_cast(unsigned short, h);
}
__device__ inline float bf2f(unsigned short u) {
    unsigned int x = ((unsigned int)u) << 16;
    return __builtin_bit_cast(float, x);
}

__device__ inline void block_reduce_atomic(float v, float* dst) {
    #pragma unroll
    for (int o = 32; o > 0; o >>= 1) v += __shfl_down(v, o, 64);
    __shared__ float ws[8];
    const int lane = threadIdx.x & 63;
    const int wid  = threadIdx.x >> 6;
    if (lane == 0) ws[wid] = v;
    __syncthreads();
    if (threadIdx.x == 0) {
        float s = 0.f;
        const int nw = (blockDim.x + 63) >> 6;
        for (int i = 0; i < nw; ++i) s += ws[i];
        atomicAdd(dst, s);
    }
}

// ---------------------------------------------------------------------------
// small kernels
// ---------------------------------------------------------------------------
__global__ void zero_accs_kernel(float* accs) {
    if (threadIdx.x < 8) accs[threadIdx.x] = 0.f;
}

__global__ void mse_kernel(const float* __restrict__ a, const float* __restrict__ b,
                           float* __restrict__ acc, int n) {
    float s = 0.f;
    for (int i = blockIdx.x * blockDim.x + threadIdx.x; i < n; i += gridDim.x * blockDim.x) {
        float d = a[i] - b[i];
        s += d * d;
    }
    block_reduce_atomic(s, acc);
}

__global__ void ssim_kernel(const float* __restrict__ x, const float* __restrict__ y,
                            float* __restrict__ acc) {
    const int b = blockIdx.y;
    const int t = blockIdx.x * blockDim.x + threadIdx.x;
    float S = 0.f;
    if (t < 250 * 250) {
        const int i = t / 250, j = t - (t / 250) * 250;
        const float* xp = x + (size_t)b * 65536;
        const float* yp = y + (size_t)b * 65536;
        float sx = 0.f, sy = 0.f, sxx = 0.f, syy = 0.f, sxy = 0.f;
        #pragma unroll
        for (int dy = 0; dy < 7; ++dy) {
            const float* xr = xp + (size_t)(i + dy) * 256 + j;
            const float* yr = yp + (size_t)(i + dy) * 256 + j;
            #pragma unroll
            for (int dx = 0; dx < 7; ++dx) {
                float a = xr[dx], c = yr[dx];
                sx += a; sy += c;
                sxx += a * a; syy += c * c; sxy += a * c;
            }
        }
        const float inv = 1.f / 49.f;
        const float cn  = 49.f / 48.f;
        float ux = sx * inv, uy = sy * inv;
        float vx  = cn * (sxx * inv - ux * ux);
        float vy  = cn * (syy * inv - uy * uy);
        float vxy = cn * (sxy * inv - ux * uy);
        const float C1 = 1e-4f, C2 = 9e-4f;
        S = ((2.f * ux * uy + C1) * (2.f * vxy + C2)) /
            ((ux * ux + uy * uy + C1) * (vx + vy + C2));
    }
    block_reduce_atomic(S, acc);
}

__global__ void sqdiff_kernel(const bf16* __restrict__ a, const bf16* __restrict__ b,
                              float* __restrict__ acc, int n) {
    float s = 0.f;
    for (int i = blockIdx.x * blockDim.x + threadIdx.x; i < n; i += gridDim.x * blockDim.x) {
        float d = __bfloat162float(a[i]) - __bfloat162float(b[i]);
        s += d * d;
    }
    block_reduce_atomic(s, acc);
}

__global__ void finalize_kernel(const float* __restrict__ accs, float* __restrict__ out) {
    if (threadIdx.x == 0) {
        float mse    = accs[0] * (1.f / 524288.f);
        float ssim_l = 1.f - accs[1] * (1.f / 500000.f);
        float perc   = accs[2] * (1.f / 33554432.f);
        out[0] = mse + 0.5f * ssim_l + 0.1f * perc;
        out[1] = mse;
        out[2] = ssim_l;
        out[3] = perc;
    }
}

// repack weights (CO,CIN,3,3) fp32 -> (CO, 9, CIN) bf16
__global__ void wprep_kernel(const float* __restrict__ w, bf16* __restrict__ wb,
                             int CIN, int CO) {
    int idx = blockIdx.x * blockDim.x + threadIdx.x;
    int n = CO * 9 * CIN;
    if (idx >= n) return;
    int ci = idx % CIN;
    int t  = (idx / CIN) % 9;
    int co = idx / (9 * CIN);
    wb[idx] = __float2bfloat16(w[((size_t)co * CIN + ci) * 9 + t]);
}

// ---------------------------------------------------------------------------
// conv1: CIN=1, CO=64, fp32 NCHW in -> bf16 NHWC out, relu
// one thread per pixel; grid (H*W/256, NIMG)
// ---------------------------------------------------------------------------
__global__ __launch_bounds__(256) void conv1_kernel(
    const float* __restrict__ sr, const float* __restrict__ hr, int nb, int b0,
    const float* __restrict__ w, const float* __restrict__ bias,
    bf16* __restrict__ out) {
    const int H = 256, W = 256;
    const int img = blockIdx.y;
    const float* in = (img < nb) ? (sr + (size_t)(b0 + img) * 65536)
                                 : (hr + (size_t)(b0 + img - nb) * 65536);
    int px = blockIdx.x * 256 + threadIdx.x;
    int y = px >> 8, x = px & 255;
    float p[9];
    #pragma unroll
    for (int dy = 0; dy < 3; ++dy)
        #pragma unroll
        for (int dx = 0; dx < 3; ++dx) {
            int gy = y + dy - 1, gx = x + dx - 1;
            float v = 0.f;
            if ((unsigned)gy < (unsigned)H && (unsigned)gx < (unsigned)W)
                v = in[(size_t)gy * W + gx];
            p[dy * 3 + dx] = v;
        }
    bf16* op = out + ((size_t)img * H * W + px) * 64;
    #pragma unroll
    for (int c8 = 0; c8 < 8; ++c8) {
        us8 o;
        #pragma unroll
        for (int c = 0; c < 8; ++c) {
            int co = c8 * 8 + c;
            float a = bias[co];
            #pragma unroll
            for (int k = 0; k < 9; ++k) a += w[co * 9 + k] * p[k];
            o[c] = f2bf(fmaxf(a, 0.f));
        }
        *(us8*)(op + c8 * 8) = o;
    }
}

// ---------------------------------------------------------------------------
// implicit-GEMM 3x3 SAME conv, NHWC bf16 -> NHWC bf16, bias+relu.
// block: 256 thr = 4 waves (2x2), tile 128 co x (8 rows x 16 cols) px.
// K-loop over ci in steps of 32; LDS holds 10x18 halo patch, 80 B/pixel pad.
// weights pre-packed (CO, 9, CIN) bf16; tap offsets are compile-time imms.
// ---------------------------------------------------------------------------
template <int CIN>
__global__ __launch_bounds__(256) void conv_mfma_kernel(
    const bf16* __restrict__ in,    // (NIMG, H, W, CIN)
    const bf16* __restrict__ wb,    // (CO, 9, CIN)
    const float* __restrict__ bias, // (CO)
    bf16* __restrict__ out,         // (NIMG, H, W, CO)
    int H, int W, int CO) {
    const int tid  = threadIdx.x;
    const int lane = tid & 63;
    const int wave = tid >> 6;
    const int wm = wave & 1, wn = wave >> 1;
    const int x0 = blockIdx.x * 16;
    const int y0 = blockIdx.y * 8;
    const int nco = CO >> 7;
    const int img = blockIdx.z / nco;
    const int co0 = (blockIdx.z - img * nco) << 7;

    __shared__ __align__(16) char smem[10 * 18 * 80];

    f32x4 acc[4][4];
    #pragma unroll
    for (int i = 0; i < 4; ++i)
        #pragma unroll
        for (int j = 0; j < 4; ++j) acc[i][j] = (f32x4){0.f, 0.f, 0.f, 0.f};

    const bf16* inp = in + (size_t)img * H * W * CIN;

    // A (weights) per-lane base: co row + k-half, positioned at tap t=4
    const int coA = co0 + wm * 64 + (lane & 15);
    const int kA  = (lane >> 4) * 8;
    const bf16* wbase0 = wb + ((size_t)coA * 9 + 4) * CIN + kA;

    // B (input) per-lane LDS base byte offset (dy=dx=0, nt=0)
    const int boff = (wn * 4) * 18 * 80 + (lane & 15) * 80 + (lane >> 4) * 16;

    for (int ci0 = 0; ci0 < CIN; ci0 += 32) {
        // ---- stage 10x18x32 halo patch (zero-padded) ----
        #pragma unroll
        for (int k = 0; k < 3; ++k) {
            int c = tid + k * 256;
            if (c < 720) {
                int q = c & 3, pxl = (c >> 2) % 18, row = c / 72;
                int gy = y0 - 1 + row, gx = x0 - 1 + pxl;
                uint4 v = {0u, 0u, 0u, 0u};
                if ((unsigned)gy < (unsigned)H && (unsigned)gx < (unsigned)W)
                    v = *(const uint4*)(inp + ((size_t)gy * W + gx) * CIN + ci0 + q * 8);
                *(uint4*)(smem + (row * 18 + pxl) * 80 + q * 16) = v;
            }
        }
        __syncthreads();

        const bf16* wci = wbase0 + ci0;
        #pragma unroll
        for (int t = 0; t < 9; ++t) {
            const int dy = t / 3, dx = t - dy * 3;
            bf16x8 a[4], b[4];
            #pragma unroll
            for (int mt = 0; mt < 4; ++mt)
                a[mt] = *(const bf16x8*)(wci + (size_t)mt * 16 * 9 * CIN + (t - 4) * CIN);
            #pragma unroll
            for (int nt = 0; nt < 4; ++nt)
                b[nt] = *(const bf16x8*)(smem + boff + ((nt + dy) * 18 + dx) * 80);
            #pragma unroll
            for (int mt = 0; mt < 4; ++mt)
                #pragma unroll
                for (int nt = 0; nt < 4; ++nt)
                    acc[mt][nt] = __builtin_amdgcn_mfma_f32_16x16x32_bf16(
                        a[mt], b[nt], acc[mt][nt], 0, 0, 0);
        }
        __syncthreads();
    }

    // ---- epilogue: bias + relu, pack 4 consecutive co, NHWC store ----
    #pragma unroll
    for (int mt = 0; mt < 4; ++mt) {
        const int co = co0 + wm * 64 + mt * 16 + (lane >> 4) * 4;
        const f32x4 bv = *(const f32x4*)(bias + co);
        #pragma unroll
        for (int nt = 0; nt < 4; ++nt) {
            const int y = y0 + wn * 4 + nt;
            const int x = x0 + (lane & 15);
            us4 o;
            #pragma unroll
            for (int r = 0; r < 4; ++r)
                o[r] = f2bf(fmaxf(acc[mt][nt][r] + bv[r], 0.f));
            *(us4*)(out + ((size_t)img * H * W + (size_t)y * W + x) * CO + co) = o;
        }
    }
}

// 2x2 maxpool, NHWC bf16, (NIMG,256,256,128) -> (NIMG,128,128,128)
__global__ __launch_bounds__(256) void pool_kernel(
    const bf16* __restrict__ in, bf16* __restrict__ out, int total) {
    int idx = blockIdx.x * 256 + threadIdx.x;   // one 8-channel chunk
    if (idx >= total) return;
    int c8 = idx & 15;
    int opx = idx >> 4;
    int ox = opx & 127, oy = (opx >> 7) & 127, img = opx >> 14;
    const bf16* ip = in + (((size_t)img * 256 + 2 * oy) * 256 + 2 * ox) * 128 + c8 * 8;
    us8 v0 = *(const us8*)(ip);
    us8 v1 = *(const us8*)(ip + 128);
    us8 v2 = *(const us8*)(ip + 256 * 128);
    us8 v3 = *(const us8*)(ip + 256 * 128 + 128);
    us8 o;
    #pragma unroll
    for (int k = 0; k < 8; ++k) {
        float m = fmaxf(fmaxf(bf2f(v0[k]), bf2f(v1[k])),
                        fmaxf(bf2f(v2[k]), bf2f(v3[k])));
        o[k] = f2bf(m);
    }
    *(us8*)(out + ((size_t)opx) * 128 + c8 * 8) = o;
}

// ---------------------------------------------------------------------------
// launch
// ---------------------------------------------------------------------------
extern "C" void kernel_launch(void* const* d_in, const int* in_sizes, int n_in,
                              void* d_out, int out_size, void* d_ws, size_t ws_size,
                              hipStream_t stream) {
    const float* sr = (const float*)d_in[0];
    const float* hr = (const float*)d_in[1];
    const float* w1 = (const float*)d_in[2];
    const float* b1 = (const float*)d_in[3];
    const float* w2 = (const float*)d_in[4];
    const float* b2 = (const float*)d_in[5];
    const float* w3 = (const float*)d_in[6];
    const float* b3 = (const float*)d_in[7];
    const float* w4 = (const float*)d_in[8];
    const float* b4 = (const float*)d_in[9];
    float* out = (float*)d_out;

    char* ws = (char*)d_ws;
    size_t off = 0;
    float* accs = (float*)(ws + off); off += 256;
    bf16* wb2 = (bf16*)(ws + off); off += (size_t)128 * 9 * 64 * 2;
    bf16* wb3 = (bf16*)(ws + off); off += (size_t)256 * 9 * 128 * 2;
    bf16* wb4 = (bf16*)(ws + off); off += (size_t)256 * 9 * 256 * 2;
    const size_t fixed = off;

    const size_t MB = 1024u * 1024u;
    // per chunk (2*nb images): A = 2nb*8MB, B = 2nb*16MB, C = 2nb*4MB
    int nb = 8;
    while (nb > 1 && fixed + (size_t)nb * 2 * 28 * MB > ws_size) nb >>= 1;

    bf16* A  = (bf16*)(ws + fixed);
    bf16* Bb = (bf16*)(ws + fixed + (size_t)nb * 2 * 8 * MB);
    bf16* C  = (bf16*)(ws + fixed + (size_t)nb * 2 * 24 * MB);

    zero_accs_kernel<<<1, 32, 0, stream>>>(accs);
    wprep_kernel<<<288, 256, 0, stream>>>(w2, wb2, 64, 128);
    wprep_kernel<<<1152, 256, 0, stream>>>(w3, wb3, 128, 256);
    wprep_kernel<<<2304, 256, 0, stream>>>(w4, wb4, 256, 256);
    mse_kernel<<<2048, 256, 0, stream>>>(sr, hr, accs + 0, 524288);
    ssim_kernel<<<dim3(245, 8), 256, 0, stream>>>(sr, hr, accs + 1);

    for (int b0 = 0; b0 < 8; b0 += nb) {
        const int ni = 2 * nb;  // sr images then hr images
        // conv1 -> A (ni,256,256,64)
        conv1_kernel<<<dim3(256, ni), 256, 0, stream>>>(sr, hr, nb, b0, w1, b1, A);
        // conv2 -> Bb (ni,256,256,128)
        conv_mfma_kernel<64><<<dim3(16, 32, ni), 256, 0, stream>>>(
            A, wb2, b2, Bb, 256, 256, 128);
        // pool -> C (ni,128,128,128)
        pool_kernel<<<(ni * 128 * 128 * 16 + 255) / 256, 256, 0, stream>>>(
            Bb, C, ni * 128 * 128 * 16);
        // conv3 -> A (ni,128,128,256)
        conv_mfma_kernel<128><<<dim3(8, 16, ni * 2), 256, 0, stream>>>(
            C, wb3, b3, A, 128, 128, 256);
        // conv4 -> Bb (ni,128,128,256)
        conv_mfma_kernel<256><<<dim3(8, 16, ni * 2), 256, 0, stream>>>(
            A, wb4, b4, Bb, 128, 128, 256);
        // perceptual partial: sum((F_sr - F_hr)^2)
        sqdiff_kernel<<<4096, 256, 0, stream>>>(
            Bb, Bb + (size_t)nb * 4194304, accs + 2, nb * 4194304);
    }

    finalize_kernel<<<1, 1, 0, stream>>>(accs, out);
}